// Round 1
// baseline (732.525 us; speedup 1.0000x reference)
//
#include <hip/hip_runtime.h>
#include <stdint.h>
#include <stddef.h>

// SwinV2-B stage-3 window attention, MI355X bf16-MFMA pipeline.
// ws layout (requires ws_size >= ~409 MB):
//   [0)            QKV bf16 [131072][1536]  (q|k|v cols; attn overwrites q-cols with its output)
//   [402653184)    CMB  f32 [16w][16h][64][64]  combined 16*sigmoid(cpb)+mask
//   [406847488)    SIG  f32 [225][16]
//   [406861888)    WQB  bf16 [1536][512]   qkv_w
//   [408434752)    WPB  bf16 [512][512]    proj_w

typedef __attribute__((ext_vector_type(8))) short bf16x8;
typedef __attribute__((ext_vector_type(4))) float f32x4;
typedef __attribute__((ext_vector_type(4))) unsigned short us4;
typedef __attribute__((ext_vector_type(8))) unsigned short us8;
typedef unsigned short u16;
typedef unsigned int u32;

__device__ __forceinline__ u16 f2bf(float f) {
  union { __bf16 b; u16 u; } cv;
  cv.b = (__bf16)f;            // hardware RNE convert on gfx950
  return cv.u;
}
__device__ __forceinline__ float bf2f(u16 s) {
  return __uint_as_float(((u32)s) << 16);
}
__device__ __forceinline__ void gl_lds16(const void* g, void* l) {
  __builtin_amdgcn_global_load_lds(
      (const __attribute__((address_space(1))) u32*)g,
      (__attribute__((address_space(3))) u32*)l, 16, 0, 0);
}
__device__ __forceinline__ f32x4 mfma16(bf16x8 a, bf16x8 b, f32x4 c) {
  return __builtin_amdgcn_mfma_f32_16x16x32_bf16(a, b, c, 0, 0, 0);
}

// ---------------- prep kernels ----------------

__global__ void conv_w_kernel(const float* __restrict__ QW, const float* __restrict__ PW,
                              u16* __restrict__ WQB, u16* __restrict__ WPB) {
  int idx = blockIdx.x * 256 + threadIdx.x;   // 262144 float4 chunks total
  const int NQ = 1536 * 512 / 4;              // 196608
  float4 v; u16* dst;
  if (idx < NQ) { v = ((const float4*)QW)[idx]; dst = WQB + (size_t)idx * 4; }
  else { int k = idx - NQ; v = ((const float4*)PW)[k]; dst = WPB + (size_t)k * 4; }
  us4 u; u.x = f2bf(v.x); u.y = f2bf(v.y); u.z = f2bf(v.z); u.w = f2bf(v.w);
  *(us4*)dst = u;
}

__global__ void sig16_kernel(const float* __restrict__ CT, const float* __restrict__ W1,
                             const float* __restrict__ B1, const float* __restrict__ W2,
                             float* __restrict__ SIG) {
  int i = blockIdx.x;            // 0..224
  int tid = threadIdx.x;         // 256
  float c0 = CT[i * 2 + 0], c1 = CT[i * 2 + 1];
  float a[16];
  #pragma unroll
  for (int hh = 0; hh < 16; ++hh) a[hh] = 0.f;
  #pragma unroll
  for (int jj = 0; jj < 2; ++jj) {
    int j = tid + jj * 256;
    float h = fmaxf(c0 * W1[j * 2 + 0] + c1 * W1[j * 2 + 1] + B1[j], 0.f);
    #pragma unroll
    for (int hh = 0; hh < 16; ++hh) a[hh] += h * W2[hh * 512 + j];
  }
  __shared__ float red[4][16];
  #pragma unroll
  for (int hh = 0; hh < 16; ++hh) {
    float v = a[hh];
    for (int m = 1; m < 64; m <<= 1) v += __shfl_xor(v, m);
    if ((tid & 63) == 0) red[tid >> 6][hh] = v;
  }
  __syncthreads();
  if (tid < 16) {
    float v = red[0][tid] + red[1][tid] + red[2][tid] + red[3][tid];
    SIG[i * 16 + tid] = 16.f / (1.f + __expf(-v));
  }
}

__global__ void cmb_kernel(const float* __restrict__ SIG, const float* __restrict__ MASK,
                           const int* __restrict__ RPI, float* __restrict__ CMB) {
  int b = blockIdx.x;            // (w,h) = 256 blocks
  int w = b >> 4, h = b & 15;
  int tid = threadIdx.x;
  const float* mrow = &MASK[(size_t)w * 4096];
  float* crow = &CMB[(size_t)b * 4096];
  #pragma unroll
  for (int it = 0; it < 16; ++it) {
    int nm = it * 256 + tid;
    crow[nm] = SIG[RPI[nm] * 16 + h] + mrow[nm];
  }
}

// ---------------- qkv GEMM: [131072,512]f32 @ WQB^T -> bf16 [131072,1536] ----------------
// 128x128 tile, BK=64, 4 waves (2x2 of 64x64), m97-style single-buffer 2-barrier loop.

__global__ __launch_bounds__(256, 2) void qkv_gemm(
    const float* __restrict__ X, const u16* __restrict__ WB,
    const float* __restrict__ QB, const float* __restrict__ VB,
    u16* __restrict__ QKV) {
  __shared__ u16 As[128 * 64];   // [m][k]
  __shared__ u16 Bs[128 * 64];   // [n][k]
  const int tid = threadIdx.x, lane = tid & 63, w = tid >> 6;
  int bid = blockIdx.x;
  int swz = (bid & 7) * 1536 + (bid >> 3);       // 12288 wgs, bijective XCD swizzle
  const int mt = swz / 12, nt = swz - mt * 12;
  const long m0 = (long)mt * 128, n0 = (long)nt * 128;
  const int wm = w >> 1, wn = w & 1;
  const f32x4 zf = {0.f, 0.f, 0.f, 0.f};

  f32x4 acc[4][4];
  #pragma unroll
  for (int mi = 0; mi < 4; ++mi)
    #pragma unroll
    for (int ni = 0; ni < 4; ++ni) acc[mi][ni] = zf;

  const u16* Ap = &As[(wm * 64 + (lane & 15)) * 64 + ((lane >> 4) * 8)];
  const u16* Bp = &Bs[(wn * 64 + (lane & 15)) * 64 + ((lane >> 4) * 8)];

  for (int t = 0; t < 8; ++t) {
    float4 av[8];
    #pragma unroll
    for (int i = 0; i < 8; ++i) {                 // issue A loads (f32)
      int ch = tid + (i << 8);
      int row = ch >> 4, kc = ch & 15;
      av[i] = *(const float4*)&X[(m0 + row) * 512 + t * 64 + kc * 4];
    }
    #pragma unroll
    for (int i = 0; i < 4; ++i) {                 // B direct-to-LDS
      int ch = ((w << 2) + i) * 64 + lane;
      int row = ch >> 3, kc = ch & 7;
      gl_lds16(&WB[(n0 + row) * 512 + t * 64 + kc * 8], &Bs[((w << 2) + i) * 512]);
    }
    #pragma unroll
    for (int i = 0; i < 8; ++i) {                 // A cvt + LDS write
      int ch = tid + (i << 8);
      int row = ch >> 4, kc = ch & 15;
      us4 u; u.x = f2bf(av[i].x); u.y = f2bf(av[i].y); u.z = f2bf(av[i].z); u.w = f2bf(av[i].w);
      *(us4*)&As[row * 64 + kc * 4] = u;
    }
    __syncthreads();
    #pragma unroll
    for (int ks = 0; ks < 2; ++ks) {
      bf16x8 af[4], bfr[4];
      #pragma unroll
      for (int mi = 0; mi < 4; ++mi) af[mi] = *(const bf16x8*)&Ap[mi * 1024 + ks * 32];
      #pragma unroll
      for (int ni = 0; ni < 4; ++ni) bfr[ni] = *(const bf16x8*)&Bp[ni * 1024 + ks * 32];
      #pragma unroll
      for (int mi = 0; mi < 4; ++mi)
        #pragma unroll
        for (int ni = 0; ni < 4; ++ni)
          acc[mi][ni] = mfma16(af[mi], bfr[ni], acc[mi][ni]);
    }
    __syncthreads();
  }

  #pragma unroll
  for (int ni = 0; ni < 4; ++ni) {
    const long c = n0 + wn * 64 + ni * 16 + (lane & 15);
    float bias = (c < 512) ? QB[c] : (c < 1024 ? 0.f : VB[c - 1024]);
    #pragma unroll
    for (int mi = 0; mi < 4; ++mi)
      #pragma unroll
      for (int r = 0; r < 4; ++r) {
        long row = m0 + wm * 64 + mi * 16 + (lane >> 4) * 4 + r;
        QKV[row * 1536 + c] = f2bf(acc[mi][ni][r] + bias);
      }
  }
}

// ---------------- attention: 1 block per window, 4 waves coop per head ----------------

__global__ __launch_bounds__(256, 4) void attn_kernel(
    u16* __restrict__ QKV, const float* __restrict__ CMB, const float* __restrict__ LS) {
  __shared__ u16 sm[7424];       // 14848 B
  u16* qs = sm;                  // [64][40] (aliased by ps)
  u16* ksm = sm + 2560;          // [64][40] (aliased by ps)
  u16* ps = sm;                  // [64][72]
  u16* vt = sm + 5120;           // [32][72] (v transposed: [d][k])
  const int tid = threadIdx.x, lane = tid & 63, w = tid >> 6;
  const int b = blockIdx.x, wi = b & 15;
  const size_t base = (size_t)b * 64 * 1536;
  const int cl = lane & 15, lg = lane >> 4;
  const int srow = tid >> 2, sck = tid & 3;       // q/k staging: 4 threads per row
  const int vd = tid & 31, vkb = tid >> 5;        // v transpose staging
  const f32x4 zf = {0.f, 0.f, 0.f, 0.f};

  for (int h = 0; h < 16; ++h) {
    const float scale = __expf(fminf(LS[h], 4.6051702f));   // min(log s, log 100)
    { // q: load row, normalize (f32), *scale, -> LDS bf16
      us8 qv = *(const us8*)&QKV[base + (size_t)srow * 1536 + h * 32 + sck * 8];
      float qf[8]; float ss = 0.f;
      #pragma unroll
      for (int j = 0; j < 8; ++j) { qf[j] = bf2f(qv[j]); ss += qf[j] * qf[j]; }
      ss += __shfl_xor(ss, 1); ss += __shfl_xor(ss, 2);
      float rn = scale / fmaxf(sqrtf(ss), 1e-12f);
      us8 qo;
      #pragma unroll
      for (int j = 0; j < 8; ++j) qo[j] = f2bf(qf[j] * rn);
      *(us8*)&qs[srow * 40 + sck * 8] = qo;
    }
    { // k: normalize
      us8 kv = *(const us8*)&QKV[base + (size_t)srow * 1536 + 512 + h * 32 + sck * 8];
      float kf[8]; float ss = 0.f;
      #pragma unroll
      for (int j = 0; j < 8; ++j) { kf[j] = bf2f(kv[j]); ss += kf[j] * kf[j]; }
      ss += __shfl_xor(ss, 1); ss += __shfl_xor(ss, 2);
      float rn = 1.f / fmaxf(sqrtf(ss), 1e-12f);
      us8 ko;
      #pragma unroll
      for (int j = 0; j < 8; ++j) ko[j] = f2bf(kf[j] * rn);
      *(us8*)&ksm[srow * 40 + sck * 8] = ko;
    }
    { // v: gather column vd (8 k's), write transposed row
      us8 vo;
      #pragma unroll
      for (int e = 0; e < 8; ++e)
        vo[e] = QKV[base + (size_t)(vkb * 8 + e) * 1536 + 1024 + h * 32 + vd];
      *(us8*)&vt[vd * 72 + vkb * 8] = vo;
    }
    __syncthreads();

    // QK^T: wave w owns rows [16w,16w+16)
    bf16x8 aq = *(const bf16x8*)&qs[(w * 16 + cl) * 40 + lg * 8];
    f32x4 s4[4];
    #pragma unroll
    for (int nt = 0; nt < 4; ++nt) {
      bf16x8 bk = *(const bf16x8*)&ksm[(nt * 16 + cl) * 40 + lg * 8];
      s4[nt] = mfma16(aq, bk, zf);
    }

    // + combined bias/mask, softmax in registers
    const float* cp = &CMB[((size_t)(wi * 16 + h)) << 12];
    const int r0 = w * 16 + lg * 4;
    float p[4][4];
    #pragma unroll
    for (int r = 0; r < 4; ++r) {
      float mx = -3.0e38f;
      #pragma unroll
      for (int q4 = 0; q4 < 4; ++q4) {
        float v = s4[q4][r] + cp[(r0 + r) * 64 + q4 * 16 + cl];
        p[q4][r] = v; mx = fmaxf(mx, v);
      }
      mx = fmaxf(mx, __shfl_xor(mx, 1));
      mx = fmaxf(mx, __shfl_xor(mx, 2));
      mx = fmaxf(mx, __shfl_xor(mx, 4));
      mx = fmaxf(mx, __shfl_xor(mx, 8));
      float sum = 0.f;
      #pragma unroll
      for (int q4 = 0; q4 < 4; ++q4) { float e = __expf(p[q4][r] - mx); p[q4][r] = e; sum += e; }
      sum += __shfl_xor(sum, 1); sum += __shfl_xor(sum, 2);
      sum += __shfl_xor(sum, 4); sum += __shfl_xor(sum, 8);
      float inv = 1.f / sum;
      #pragma unroll
      for (int q4 = 0; q4 < 4; ++q4) p[q4][r] *= inv;
    }
    __syncthreads();   // all waves done reading qs/ks before ps overwrite

    #pragma unroll
    for (int r = 0; r < 4; ++r)
      #pragma unroll
      for (int q4 = 0; q4 < 4; ++q4)
        ps[(r0 + r) * 72 + q4 * 16 + cl] = f2bf(p[q4][r]);

    // PV: out[64x32]; reads own-wave ps rows + shared vt
    f32x4 o4[2]; o4[0] = zf; o4[1] = zf;
    #pragma unroll
    for (int ks = 0; ks < 2; ++ks) {
      bf16x8 ap = *(const bf16x8*)&ps[(w * 16 + cl) * 72 + ks * 32 + lg * 8];
      #pragma unroll
      for (int n2 = 0; n2 < 2; ++n2) {
        bf16x8 bv = *(const bf16x8*)&vt[(n2 * 16 + cl) * 72 + ks * 32 + lg * 8];
        o4[n2] = mfma16(ap, bv, o4[n2]);
      }
    }
    // store attn-out over the q-region (cols h*32..h*32+31) of this window's rows
    #pragma unroll
    for (int n2 = 0; n2 < 2; ++n2)
      #pragma unroll
      for (int r = 0; r < 4; ++r)
        QKV[base + (size_t)(w * 16 + lg * 4 + r) * 1536 + h * 32 + n2 * 16 + cl] = f2bf(o4[n2][r]);
    __syncthreads();   // before next head's staging overwrites LDS
  }
}

// ---------------- proj GEMM: bf16 [131072,512](lda=1536) @ WPB^T + b -> f32 out ----------------

__global__ __launch_bounds__(256, 2) void proj_gemm(
    const u16* __restrict__ A, const u16* __restrict__ WB,
    const float* __restrict__ PB, float* __restrict__ OUT) {
  __shared__ u16 As[128 * 64];
  __shared__ u16 Bs[128 * 64];
  const int tid = threadIdx.x, lane = tid & 63, w = tid >> 6;
  int bid = blockIdx.x;
  int swz = (bid & 7) * 512 + (bid >> 3);        // 4096 wgs
  const int mt = swz >> 2, nt = swz & 3;
  const long m0 = (long)mt * 128, n0 = (long)nt * 128;
  const int wm = w >> 1, wn = w & 1;
  const f32x4 zf = {0.f, 0.f, 0.f, 0.f};

  f32x4 acc[4][4];
  #pragma unroll
  for (int mi = 0; mi < 4; ++mi)
    #pragma unroll
    for (int ni = 0; ni < 4; ++ni) acc[mi][ni] = zf;

  const u16* Ap = &As[(wm * 64 + (lane & 15)) * 64 + ((lane >> 4) * 8)];
  const u16* Bp = &Bs[(wn * 64 + (lane & 15)) * 64 + ((lane >> 4) * 8)];

  for (int t = 0; t < 8; ++t) {
    #pragma unroll
    for (int i = 0; i < 4; ++i) {
      int ch = ((w << 2) + i) * 64 + lane;
      int row = ch >> 3, kc = ch & 7;
      gl_lds16(&A[(m0 + row) * 1536 + t * 64 + kc * 8], &As[((w << 2) + i) * 512]);
      gl_lds16(&WB[(n0 + row) * 512 + t * 64 + kc * 8], &Bs[((w << 2) + i) * 512]);
    }
    __syncthreads();
    #pragma unroll
    for (int ks = 0; ks < 2; ++ks) {
      bf16x8 af[4], bfr[4];
      #pragma unroll
      for (int mi = 0; mi < 4; ++mi) af[mi] = *(const bf16x8*)&Ap[mi * 1024 + ks * 32];
      #pragma unroll
      for (int ni = 0; ni < 4; ++ni) bfr[ni] = *(const bf16x8*)&Bp[ni * 1024 + ks * 32];
      #pragma unroll
      for (int mi = 0; mi < 4; ++mi)
        #pragma unroll
        for (int ni = 0; ni < 4; ++ni)
          acc[mi][ni] = mfma16(af[mi], bfr[ni], acc[mi][ni]);
    }
    __syncthreads();
  }

  #pragma unroll
  for (int ni = 0; ni < 4; ++ni) {
    const long c = n0 + wn * 64 + ni * 16 + (lane & 15);
    float bias = PB[c];
    #pragma unroll
    for (int mi = 0; mi < 4; ++mi)
      #pragma unroll
      for (int r = 0; r < 4; ++r) {
        long row = m0 + wm * 64 + mi * 16 + (lane >> 4) * 4 + r;
        OUT[row * 512 + c] = acc[mi][ni][r] + bias;
      }
  }
}

// ---------------- launch ----------------

extern "C" void kernel_launch(void* const* d_in, const int* in_sizes, int n_in,
                              void* d_out, int out_size, void* d_ws, size_t ws_size,
                              hipStream_t stream) {
  const float* X    = (const float*)d_in[0];
  const float* MASK = (const float*)d_in[1];
  const float* QW   = (const float*)d_in[2];
  const float* QB   = (const float*)d_in[3];
  const float* VB   = (const float*)d_in[4];
  const float* LS   = (const float*)d_in[5];
  const float* CW1  = (const float*)d_in[6];
  const float* CB1  = (const float*)d_in[7];
  const float* CW2  = (const float*)d_in[8];
  const float* PW   = (const float*)d_in[9];
  const float* PB   = (const float*)d_in[10];
  const float* CT   = (const float*)d_in[11];
  const int*   RPI  = (const int*)d_in[12];
  float* OUT = (float*)d_out;

  char* ws = (char*)d_ws;
  u16*   QKV = (u16*)ws;                          // 402,653,184 B
  float* CMB = (float*)(ws + 402653184ull);       //   4,194,304 B
  float* SIG = (float*)(ws + 406847488ull);       //      14,400 B
  u16*   WQB = (u16*)(ws + 406861888ull);         //   1,572,864 B
  u16*   WPB = (u16*)(ws + 408434752ull);         //     524,288 B (end ~409 MB)

  conv_w_kernel<<<1024, 256, 0, stream>>>(QW, PW, WQB, WPB);
  sig16_kernel<<<225, 256, 0, stream>>>(CT, CW1, CB1, CW2, SIG);
  cmb_kernel<<<256, 256, 0, stream>>>(SIG, MASK, RPI, CMB);
  qkv_gemm<<<12288, 256, 0, stream>>>(X, WQB, QB, VB, QKV);
  attn_kernel<<<2048, 256, 0, stream>>>(QKV, CMB, LS);
  proj_gemm<<<4096, 256, 0, stream>>>(QKV, WPB, PB, OUT);
}